// Round 16
// baseline (139.009 us; speedup 1.0000x reference)
//
#include <hip/hip_runtime.h>
#include <cstdint>
#include <cstddef>

typedef uint32_t u32;
typedef uint64_t u64;

#define NB 16
#define POSTN 1000
#define PREN 1000
#define LSEG 1024     // per-level segment (1000 candidates + 24 pad)
#define LCH 16        // chunks of 64 per level
#define SIDECAP 4096  // per-task boundary-bucket buffer
#define BSIDE 2048    // per-block LDS side list
#define TRIPCAP (LSEG * LCH)  // per-task triplet capacity = full matrix
#define NPAIR 160     // triangular (chunk,g) pairs: 16+32+48+64
#define NBUCK 8192    // 13-bit histogram buckets
#define BSHIFT 19     // ord >> BSHIFT = bucket

__constant__ int c_N[4]    = {120000, 30000, 7500, 1875};
__constant__ int c_OFF[4]  = {0, 120000, 150000, 157500};
__constant__ int c_HW[4]   = {40000, 10000, 2500, 625};
__constant__ int c_W[4]    = {200, 100, 50, 25};
__constant__ int c_BASE[4] = {0, 1024, 2048, 3072};

__device__ __forceinline__ u32 ord_bits(float f) {
  u32 u = __float_as_uint(f);
  return (u & 0x80000000u) ? ~u : (u | 0x80000000u);
}
__device__ __forceinline__ float inv_ord(u32 o) {
  u32 bits = (o & 0x80000000u) ? (o ^ 0x80000000u) : ~o;
  return __uint_as_float(bits);
}
__device__ __forceinline__ u64 readlane_u64(u64 v, int l) {
  u32 lo = (u32)__builtin_amdgcn_readlane((int)(u32)v, l);
  u32 hi = (u32)__builtin_amdgcn_readlane((int)(u32)(v >> 32), l);
  return (((u64)hi) << 32) | (u64)lo;
}

// 192-block slice map: 8 blocks/task lvl0, 2/task lvl1, 1/task lvl2+3
__device__ __forceinline__ void slice_map(int bid, int& lvl, int& b, int& e0,
                                          int& nsl) {
  if (bid < 128)      { lvl = 0; b = bid >> 3; e0 = (bid & 7) * 15000; nsl = 15000; }
  else if (bid < 160) { lvl = 1; int t = bid - 128; b = t >> 1; e0 = (t & 1) * 15000; nsl = 15000; }
  else if (bid < 176) { lvl = 2; b = bid - 160; e0 = 0; nsl = 7500; }
  else                { lvl = 3; b = bid - 176; e0 = 0; nsl = 1875; }
}
// rows of histb belonging to a task
__device__ __forceinline__ void task_rows(int lvl, int b, int& row0, int& nrow) {
  if (lvl == 0)      { row0 = b << 3;         nrow = 8; }
  else if (lvl == 1) { row0 = 128 + (b << 1); nrow = 2; }
  else if (lvl == 2) { row0 = 160 + b;        nrow = 1; }
  else               { row0 = 176 + b;        nrow = 1; }
}

struct DecBox { float x1, y1, x2, y2; int lvl; bool valid; };

__device__ DecBox decode_box(u32 gid, int b,
    const float* __restrict__ reg0, const float* __restrict__ reg1,
    const float* __restrict__ reg2, const float* __restrict__ reg3,
    const float* __restrict__ anchors) {
  int lvl = (gid < 120000u) ? 0 : (gid < 150000u) ? 1 : (gid < 157500u) ? 2 : 3;
  int local = (int)gid - c_OFF[lvl];
  int a = local % 3;
  int cell = local / 3;
  int w = c_W[lvl];
  int hw = c_HW[lvl];
  int y = cell / w;
  int x = cell - y * w;
  const float* reg = (lvl == 0) ? reg0 : (lvl == 1) ? reg1 : (lvl == 2) ? reg2 : reg3;
  size_t base = ((size_t)(b * 12 + a * 4) * (size_t)w + (size_t)y) * (size_t)w + (size_t)x;
  const float CLIPV = 4.135166556742356f; // log(1000/16) as f32
  float dx = reg[base];
  float dy = reg[base + (size_t)hw];
  float dwv = fminf(reg[base + 2 * (size_t)hw], CLIPV);
  float dhv = fminf(reg[base + 3 * (size_t)hw], CLIPV);
  float a0 = anchors[(size_t)gid * 4 + 0];
  float a1 = anchors[(size_t)gid * 4 + 1];
  float a2 = anchors[(size_t)gid * 4 + 2];
  float a3 = anchors[(size_t)gid * 4 + 3];
  float wa = __fsub_rn(a2, a0);
  float ha = __fsub_rn(a3, a1);
  float cxa = __fadd_rn(a0, __fmul_rn(0.5f, wa));
  float cya = __fadd_rn(a1, __fmul_rn(0.5f, ha));
  float pcx = __fadd_rn(__fmul_rn(dx, wa), cxa);
  float pcy = __fadd_rn(__fmul_rn(dy, ha), cya);
  float pw = __fmul_rn(expf(dwv), wa);
  float ph = __fmul_rn(expf(dhv), ha);
  float x1 = __fsub_rn(pcx, __fmul_rn(0.5f, pw));
  float y1 = __fsub_rn(pcy, __fmul_rn(0.5f, ph));
  float x2 = __fadd_rn(pcx, __fmul_rn(0.5f, pw));
  float y2 = __fadd_rn(pcy, __fmul_rn(0.5f, ph));
  x1 = fminf(fmaxf(x1, 0.0f), 800.0f);
  y1 = fminf(fmaxf(y1, 0.0f), 800.0f);
  x2 = fminf(fmaxf(x2, 0.0f), 800.0f);
  y2 = fminf(fmaxf(y2, 0.0f), 800.0f);
  DecBox r;
  r.x1 = x1; r.y1 = y1; r.x2 = x2; r.y2 = y2; r.lvl = lvl;
  r.valid = (__fsub_rn(x2, x1) >= 1.0f) && (__fsub_rn(y2, y1) >= 1.0f);
  return r;
}

// ---------------- K1: per-block 13-bit histogram + fused state zeroing ---------
__global__ __launch_bounds__(1024) void k_hist1(
    const float* __restrict__ cls0, const float* __restrict__ cls1,
    const float* __restrict__ cls2, const float* __restrict__ cls3,
    u32* __restrict__ histb, float* __restrict__ out,
    u64* __restrict__ cand_key, u32* __restrict__ counters,
    u32* __restrict__ sidecnt, u32* __restrict__ tripcnt) {
  int bid = blockIdx.x;
  int tid = threadIdx.x;
  // fused zeroing of all cross-kernel state (192*1024 threads cover all)
  int g = bid * 1024 + tid;
  if (g < NB * POSTN * 5) out[g] = 0.0f;
  if (g < NB * 4096) cand_key[g] = 0ull;
  if (g < 64 * 16) { counters[g] = 0u; sidecnt[g] = 0u; tripcnt[g] = 0u; }
  int lvl, b, e0, nsl;
  slice_map(bid, lvl, b, e0, nsl);
  const float* cls = (lvl == 0) ? cls0 : (lvl == 1) ? cls1 : (lvl == 2) ? cls2 : cls3;
  const float* cp = cls + (size_t)b * c_N[lvl];
  __shared__ u32 h[NBUCK];
  for (int t = tid; t < NBUCK; t += 1024) h[t] = 0u;
  __syncthreads();
  if (lvl != 3) {
    // base offsets are 16B-aligned for lvl 0..2 (all multiples of 4 elems)
    const float4* cp4 = (const float4*)(cp + e0);
    int n4 = nsl >> 2;
    for (int t = tid; t < n4; t += 1024) {
      float4 v = cp4[t];
      atomicAdd(&h[ord_bits(v.x) >> BSHIFT], 1u);
      atomicAdd(&h[ord_bits(v.y) >> BSHIFT], 1u);
      atomicAdd(&h[ord_bits(v.z) >> BSHIFT], 1u);
      atomicAdd(&h[ord_bits(v.w) >> BSHIFT], 1u);
    }
  } else {
    for (int e = e0 + tid; e < e0 + nsl; e += 1024)
      atomicAdd(&h[ord_bits(cp[e]) >> BSHIFT], 1u);
  }
  __syncthreads();
  // plain stores of the full private histogram row — no pre-zero, no atomics
  for (int t = tid; t < NBUCK; t += 1024)
    histb[(size_t)bid * NBUCK + t] = h[t];
}

// ---------------- K2: pick boundary bucket — sum rows + O(N) suffix scan -------
__global__ __launch_bounds__(1024) void k_pick1(
    const u32* __restrict__ histb, u32* __restrict__ state_known,
    u32* __restrict__ state_kneed) {
  int task = blockIdx.x;
  int lvl = task >> 4;
  int b = task & 15;
  int tid = threadIdx.x;
  __shared__ u32 h[NBUCK];      // 32 KB
  __shared__ u32 spA[1024];
  __shared__ u32 spB[1024];
  __shared__ int sh_t;
  __shared__ u32 sh_above;
  int row0r, nrow;
  task_rows(lvl, b, row0r, nrow);
  for (int t = tid; t < NBUCK; t += 1024) {
    u32 s = 0;
    for (int r = 0; r < nrow; ++r) s += histb[(size_t)(row0r + r) * NBUCK + t];
    h[t] = s;
  }
  __syncthreads();
  u32 kneed = (u32)PREN;
  int base = tid << 3;          // 8 buckets per thread
  u32 part = 0;
#pragma unroll
  for (int j = 0; j < 8; ++j) part += h[base + j];
  spA[tid] = part;
  __syncthreads();
  // suffix scan over 1024 partials (ping-pong, 10 rounds)
  u32* cur = spA;
  u32* nxt = spB;
  for (int off = 1; off < 1024; off <<= 1) {
    u32 v = cur[tid] + ((tid + off < 1024) ? cur[tid + off] : 0u);
    nxt[tid] = v;
    __syncthreads();
    u32* tmp = cur; cur = nxt; nxt = tmp;
  }
  u32 suf = (tid + 1 < 1024) ? cur[tid + 1] : 0u;
#pragma unroll
  for (int j = 7; j >= 0; --j) {
    u32 s = suf + h[base + j];
    if (s >= kneed && suf < kneed) { sh_t = base + j; sh_above = suf; }
    suf = s;
  }
  __syncthreads();
  if (tid == 0) {
    state_known[task] = (u32)sh_t << BSHIFT;
    state_kneed[task] = kneed - sh_above;   // how many to take from boundary
  }
}

// ---------------- K3: collect — block-local staging, 1 atomic per block --------
__global__ __launch_bounds__(1024) void k_collect(
    const float* __restrict__ cls0, const float* __restrict__ cls1,
    const float* __restrict__ cls2, const float* __restrict__ cls3,
    const u32* __restrict__ state_known,
    const float* __restrict__ reg0, const float* __restrict__ reg1,
    const float* __restrict__ reg2, const float* __restrict__ reg3,
    const float* __restrict__ anchors, u32* __restrict__ counters,
    u32* __restrict__ sidecnt, u64* __restrict__ sidebuf,
    u64* __restrict__ cand_key) {
  int lvl, b, e0, nsl;
  slice_map(blockIdx.x, lvl, b, e0, nsl);
  int task = lvl * 16 + b;
  u32 tb = state_known[task] >> BSHIFT;
  const float* cls = (lvl == 0) ? cls0 : (lvl == 1) ? cls1 : (lvl == 2) ? cls2 : cls3;
  const float* cp = cls + (size_t)b * c_N[lvl];
  int tid = threadIdx.x;
  __shared__ u32 ldef[1024];
  __shared__ u32 lside[BSIDE];
  __shared__ u32 cdef, cside, bdef, bside;
  if (tid == 0) { cdef = 0u; cside = 0u; }
  __syncthreads();
  if (lvl != 3) {
    const float4* cp4 = (const float4*)(cp + e0);
    int n4 = nsl >> 2;
    for (int t = tid; t < n4; t += 1024) {
      float4 v4 = cp4[t];
      int ebase = e0 + (t << 2);
#pragma unroll
      for (int c = 0; c < 4; ++c) {
        float f = (c == 0) ? v4.x : (c == 1) ? v4.y : (c == 2) ? v4.z : v4.w;
        u32 bk = ord_bits(f) >> BSHIFT;
        if (bk < tb) continue;
        if (bk > tb) {
          u32 i = atomicAdd(&cdef, 1u);
          if (i < 1024u) ldef[i] = (u32)(ebase + c);
        } else {
          u32 i = atomicAdd(&cside, 1u);
          if (i < (u32)BSIDE) lside[i] = (u32)(ebase + c);
        }
      }
    }
  } else {
    for (int e = e0 + tid; e < e0 + nsl; e += 1024) {
      u32 bk = ord_bits(cp[e]) >> BSHIFT;
      if (bk < tb) continue;
      if (bk > tb) {
        u32 i = atomicAdd(&cdef, 1u);
        if (i < 1024u) ldef[i] = (u32)e;
      } else {
        u32 i = atomicAdd(&cside, 1u);
        if (i < (u32)BSIDE) lside[i] = (u32)e;
      }
    }
  }
  __syncthreads();
  if (tid == 0) bdef = atomicAdd(&counters[task * 16], min(cdef, 1024u));
  if (tid == 1) bside = atomicAdd(&sidecnt[task * 16], min(cside, (u32)BSIDE));
  __syncthreads();
  int hw = c_HW[lvl], off = c_OFF[lvl];
  u32 nd = min(cdef, 1024u);
  for (u32 i = tid; i < nd; i += 1024) {
    int e = (int)ldef[i];
    int a = e / hw;
    int cell = e - a * hw;
    u32 gid = (u32)(off + cell * 3 + a);
    u64 key = ((u64)ord_bits(cp[e]) << 32) | (u32)(~gid);
    DecBox bx = decode_box(gid, b, reg0, reg1, reg2, reg3, anchors);
    u64 skey = bx.valid ? key : (key & 0xFFFFFFFFull);
    u32 slot = bdef + i;
    if (slot < (u32)PREN)
      cand_key[(size_t)b * 4096 + c_BASE[lvl] + slot] = skey;
  }
  u32 ns = min(cside, (u32)BSIDE);
  for (u32 i = tid; i < ns; i += 1024) {
    int e = (int)lside[i];
    int a = e / hw;
    int cell = e - a * hw;
    u32 gid = (u32)(off + cell * 3 + a);
    u64 key = ((u64)ord_bits(cp[e]) << 32) | (u32)(~gid);
    u32 slot = bside + i;
    if (slot < (u32)SIDECAP) sidebuf[(size_t)task * SIDECAP + slot] = key;
  }
}

// ---------------- K sortdec: fused side-finalize + sort + decode ---------------
__global__ __launch_bounds__(1024) void k_sortdec(
    u64* __restrict__ cand_key, const u64* __restrict__ sidebuf,
    const u32* __restrict__ sidecnt, const u32* __restrict__ counters,
    const u32* __restrict__ state_kneed,
    const float* __restrict__ reg0, const float* __restrict__ reg1,
    const float* __restrict__ reg2, const float* __restrict__ reg3,
    const float* __restrict__ anchors,
    float4* __restrict__ sbox, float4* __restrict__ boffA,
    float* __restrict__ area, float* __restrict__ score,
    u64* __restrict__ vmaskl, u32* __restrict__ rnzl) {
  int bl = blockIdx.x;                 // b*4 + lvl
  int b = bl >> 2;
  int lvl = bl & 3;
  int task = lvl * 16 + b;
  int tid = threadIdx.x;
  // zero rnzl for this (b,lvl) — consumed (atomicOr) by k_maskl after us
  rnzl[(size_t)bl * LSEG + tid] = 0u;
  __shared__ u64 sside[SIDECAP];       // 32 KB
  __shared__ u64 sk[LSEG];             // 8 KB
  u32 nside = min(sidecnt[task * 16], (u32)SIDECAP);
  u32 kneed = state_kneed[task];
  u32 nab = counters[task * 16];       // nab + kneed == 1000 by construction
  u32 np2 = 64;
  while (np2 < nside) np2 <<= 1;
  for (u32 i = tid; i < np2; i += 1024)
    sside[i] = (i < nside) ? sidebuf[(size_t)task * SIDECAP + i] : 0ull;
  __syncthreads();
  // sort side keys desc (raw keys — top-k selection is pre-validity)
  for (u32 k = 2; k <= np2; k <<= 1) {
    for (u32 j = k >> 1; j > 0; j >>= 1) {
      for (u32 t = tid; t < np2 / 2; t += 1024) {
        u32 i = 2u * t - (t & (j - 1u));
        u32 l2 = i | j;
        u64 av = sside[i], bv = sside[l2];
        bool up = ((i & k) == 0u);
        if (up ? (av < bv) : (av > bv)) { sside[i] = bv; sside[l2] = av; }
      }
      __syncthreads();
    }
  }
  // validity-adjust the selected top-kneed side keys (in place, own slot only)
  if (tid < (int)kneed) {
    u64 key = sside[tid];
    u32 gid = ~((u32)key);
    DecBox bx = decode_box(gid, b, reg0, reg1, reg2, reg3, anchors);
    sside[tid] = bx.valid ? key : (key & 0xFFFFFFFFull);
  }
  u64 defk = (tid < (int)nab)
                 ? cand_key[(size_t)b * 4096 + c_BASE[lvl] + tid] : 0ull;
  __syncthreads();
  u64 kv = defk;
  if (tid >= (int)nab && tid < (int)(nab + kneed)) kv = sside[tid - nab];
  sk[tid] = kv;
  __syncthreads();
  // main 1024 bitonic sort desc
  for (u32 k = 2; k <= LSEG; k <<= 1) {
    for (u32 j = k >> 1; j > 0; j >>= 1) {
      if (tid < LSEG / 2) {
        u32 t = (u32)tid;
        u32 i = 2u * t - (t & (j - 1u));
        u32 l2 = i | j;
        u64 av = sk[i], bv = sk[l2];
        bool up = ((i & k) == 0u);
        if (up ? (av < bv) : (av > bv)) { sk[i] = bv; sk[l2] = av; }
      }
      __syncthreads();
    }
  }
  // write back sorted keys (k_nmsl reads them for kept compaction)
  u64 key = sk[tid];
  cand_key[(size_t)bl * LSEG + tid] = key;
  // decode payloads
  float4 bx4 = make_float4(0.f, 0.f, 0.f, 0.f);
  float4 bo4 = make_float4(0.f, 0.f, 0.f, 0.f);
  float ar = 0.f, sc = 0.f;
  bool vflag = false;
  if (key != 0ull) {
    u32 gid = ~((u32)key);
    vflag = (key >> 32) != 0ull;
    DecBox bx = decode_box(gid, b, reg0, reg1, reg2, reg3, anchors);
    bx4 = make_float4(bx.x1, bx.y1, bx.x2, bx.y2);
    float offv = __fmul_rn((float)bx.lvl, 801.0f);
    bo4 = make_float4(__fadd_rn(bx.x1, offv), __fadd_rn(bx.y1, offv),
                      __fadd_rn(bx.x2, offv), __fadd_rn(bx.y2, offv));
    ar = __fmul_rn(__fsub_rn(bo4.z, bo4.x), __fsub_rn(bo4.w, bo4.y));
    if (vflag) {
      float logit = inv_ord((u32)(key >> 32));
      sc = 1.0f / (1.0f + expf(-logit));
    }
  }
  size_t gi = (size_t)bl * LSEG + tid;
  sbox[gi] = bx4;
  boffA[gi] = bo4;
  area[gi] = ar;
  score[gi] = sc;
  u64 bal = __ballot(vflag ? 1 : 0);
  if ((tid & 63) == 0) vmaskl[bl * LCH + (tid >> 6)] = bal;
}

// ---------------- K maskl: triangular-mapped IoU → compact triplet list --------
// RN(inter/uni) > 0.7f  <=>  inter/uni >= B, B = 0.7f + 2^-25 (tie rounds up).
// B*(double)uni is exact (25x24 bits <= 53); comparison is bit-equivalent.
#define RPB 16
__global__ __launch_bounds__(256) void k_maskl(
    const float4* __restrict__ boffA, const float* __restrict__ area,
    ulonglong2* __restrict__ trip, u32* __restrict__ tripcnt,
    u32* __restrict__ rnzl) {
  const double Bd = 0x1.6666661p-1;   // 0.7000000178813934326171875
  int bg = blockIdx.x;
  int bl = bg / NPAIR;
  int p = bg - bl * NPAIR;
  // triangular (chunk,g) pairs: chunk c covers row-groups g < (c+1)*16
  int chunk, g;
  if (p < 16)      { chunk = 0; g = p; }
  else if (p < 48) { chunk = 1; g = p - 16; }
  else if (p < 96) { chunk = 2; g = p - 48; }
  else             { chunk = 3; g = p - 96; }
  int row0 = g * RPB;
  int tid = threadIdx.x;
  int wave = tid >> 6;
  int lane = tid & 63;
  __shared__ float4 rb[RPB];
  __shared__ float ra[RPB];
  __shared__ ulonglong2 stage[RPB * 4];   // max 64 nonzero words per block
  __shared__ u32 scount, sbase;
  if (tid == 0) scount = 0u;
  if (tid < RPB) {
    rb[tid] = boffA[(size_t)bl * LSEG + row0 + tid];
    ra[tid] = area[(size_t)bl * LSEG + row0 + tid];
  }
  __syncthreads();
  int wword = chunk * 4 + wave;
  int wmaxj = chunk * 256 + wave * 64 + 63;   // this wave's max column
  int j = chunk * 256 + tid;
  float4 cb = boffA[(size_t)bl * LSEG + j];
  float ca = area[(size_t)bl * LSEG + j];
  if (wmaxj > row0) {
#pragma unroll
    for (int rr = 0; rr < RPB; ++rr) {
      int i = row0 + rr;
      if (wmaxj <= i) continue;
      float4 rbb = rb[rr];
      float ria = ra[rr];
      float ix1 = fmaxf(cb.x, rbb.x);
      float iy1 = fmaxf(cb.y, rbb.y);
      float ix2 = fminf(cb.z, rbb.z);
      float iy2 = fminf(cb.w, rbb.w);
      float inter = __fmul_rn(fmaxf(__fsub_rn(ix2, ix1), 0.0f),
                              fmaxf(__fsub_rn(iy2, iy1), 0.0f));
      float uni = __fsub_rn(__fadd_rn(ca, ria), inter);
      bool pred = (j > i) && (inter > 0.0f) &&
                  ((double)inter >= Bd * (double)uni);
      u64 bal = __ballot(pred ? 1 : 0);
      if (lane == 0 && bal) {
        u32 sidx = atomicAdd(&scount, 1u);
        ulonglong2 e;
        e.x = bal;
        e.y = (u64)(u32)(i * LCH + wword);
        stage[sidx] = e;
        atomicOr(&rnzl[(size_t)bl * LSEG + i], 1u << wword);
      }
    }
  }
  __syncthreads();
  if (tid == 0 && scount) sbase = atomicAdd(&tripcnt[bl * 16], scount);
  __syncthreads();
  for (u32 t = tid; t < scount; t += 256)
    trip[(size_t)bl * TRIPCAP + sbase + t] = stage[t];
}

// ---------------- K nmsl: greedy NMS — full mask matrix in LDS -----------------
__global__ __launch_bounds__(64) void k_nmsl(
    const ulonglong2* __restrict__ trip, const u32* __restrict__ tripcnt,
    const u32* __restrict__ rnzl, const u64* __restrict__ vmaskl,
    const u64* __restrict__ cand_key,
    u64* __restrict__ keptkeys, u32* __restrict__ keptpos,
    u32* __restrict__ keptcnt) {
  int bl = blockIdx.x;
  int lane = threadIdx.x;
  extern __shared__ char smem[];
  u64* lmask = (u64*)smem;                       // [LSEG*LCH] = 128 KB
  u32* rnzL  = (u32*)(smem + (size_t)LSEG * LCH * 8);  // [LSEG] = 4 KB
  // zero the matrix (16B LDS writes), copy rnzl (coalesced global)
  ulonglong2 z2; z2.x = 0ull; z2.y = 0ull;
  ulonglong2* lm2 = (ulonglong2*)lmask;
  for (int t = lane; t < LSEG * LCH / 2; t += 64) lm2[t] = z2;
  for (int t = lane; t < LSEG; t += 64) rnzL[t] = rnzl[(size_t)bl * LSEG + t];
  u64 vword = (lane < LCH) ? vmaskl[bl * LCH + lane] : 0ull;
  __syncthreads();
  // scatter triplets (unique (row,word) targets — order-independent)
  u32 tc = tripcnt[bl * 16];
  for (u32 t = lane; t < tc; t += 64) {
    ulonglong2 e = trip[(size_t)bl * TRIPCAP + t];
    lmask[(u32)e.y] = e.x;
  }
  __syncthreads();
  u64 supp = 0ull;   // lane w<16 holds suppression word w
  u64 keep = 0ull;   // lane w<16 holds keep word w
  for (int W = 0; W < LCH; ++W) {
    int c0 = W << 6;
    // independent LDS reads issue early; latency hides under the shfl chain
    u32 rzW = rnzL[c0 + lane];                      // rnz of row c0+lane
    u64 dchW = lmask[(size_t)(c0 + lane) * LCH + W];  // diagonal word
    u64 s = __shfl(supp, W);
    u64 v = __shfl(vword, W);
    // greedy resolve: scalar readlane over suppressor rows only
    u64 pending = v & ~s;
    u64 kw = 0ull;
    u64 suppressors = __ballot((dchW & pending) != 0ull) & pending;
    while (pending) {
      u64 sp = pending & suppressors;
      if (!sp) { kw |= pending; break; }
      int q = __builtin_ctzll(sp);
      u64 below = pending & ((1ull << q) - 1ull);
      kw |= below | (1ull << q);
      u64 supq = readlane_u64(dchW, q);
      pending &= ~supq & ~below & ~(1ull << q);
    }
    // sparse apply: kept rows with words beyond W; 4-deep batched LDS reads
    u64 kk = __ballot(((rzW >> W) >> 1) != 0u) & kw;
    bool ld = (lane < LCH);
    u64 acc = 0ull;
    while (kk) {
      int q0 = __builtin_ctzll(kk); kk &= kk - 1ull;
      u64 m0 = ld ? lmask[(size_t)(c0 + q0) * LCH + lane] : 0ull;
      u64 m1 = 0ull, m2 = 0ull, m3 = 0ull;
      if (kk) {
        int q1 = __builtin_ctzll(kk); kk &= kk - 1ull;
        m1 = ld ? lmask[(size_t)(c0 + q1) * LCH + lane] : 0ull;
      }
      if (kk) {
        int q2 = __builtin_ctzll(kk); kk &= kk - 1ull;
        m2 = ld ? lmask[(size_t)(c0 + q2) * LCH + lane] : 0ull;
      }
      if (kk) {
        int q3 = __builtin_ctzll(kk); kk &= kk - 1ull;
        m3 = ld ? lmask[(size_t)(c0 + q3) * LCH + lane] : 0ull;
      }
      acc |= (m0 | m1) | (m2 | m3);
    }
    supp |= acc;
    if (lane == W) keep = kw;
  }
  // compact kept: prefix popcount across lanes
  int pc = __popcll(keep);
  int incl = pc;
  for (int d = 1; d < 64; d <<= 1) {
    int t = __shfl_up(incl, d);
    if (lane >= d) incl += t;
  }
  int r = incl - pc;
  u64 kk = keep;
  while (kk) {
    int bit = __builtin_ctzll(kk);
    kk &= kk - 1ull;
    int p = lane * 64 + bit;
    keptkeys[(size_t)bl * LSEG + r] = cand_key[(size_t)bl * LSEG + p];
    keptpos[(size_t)bl * LSEG + r] = (u32)p;
    ++r;
  }
  if (lane == 63) keptcnt[bl] = (u32)incl;
}

// ---------------- K out: global rank via cross-level binary search -------------
__global__ __launch_bounds__(1024) void k_out(
    const u64* __restrict__ keptkeys, const u32* __restrict__ keptpos,
    const u32* __restrict__ keptcnt, const float4* __restrict__ sbox,
    const float* __restrict__ score, float* __restrict__ out) {
  int bl = blockIdx.x;
  int b = bl >> 2;
  int l = bl & 3;
  int r = threadIdx.x;
  u32 cnt = keptcnt[bl];
  if (r >= (int)cnt) return;
  u64 K = keptkeys[(size_t)bl * LSEG + r];
  int rank = r;
#pragma unroll
  for (int dl = 0; dl < 4; ++dl) {
    if (dl == l) continue;
    int obl = (b << 2) | dl;
    const u64* arr = keptkeys + (size_t)obl * LSEG;
    int lo = 0, hi = (int)keptcnt[obl];
    while (lo < hi) {
      int mid = (lo + hi) >> 1;
      if (arr[mid] > K) lo = mid + 1; else hi = mid;
    }
    rank += lo;
  }
  if (rank < POSTN) {
    u32 p = keptpos[(size_t)bl * LSEG + r];
    float4 bx = sbox[(size_t)bl * LSEG + p];
    size_t ob = ((size_t)b * POSTN + (size_t)rank) * 4;
    out[ob + 0] = bx.x;
    out[ob + 1] = bx.y;
    out[ob + 2] = bx.z;
    out[ob + 3] = bx.w;
    out[(size_t)NB * POSTN * 4 + (size_t)b * POSTN + (size_t)rank] =
        score[(size_t)bl * LSEG + p];
  }
}

extern "C" void kernel_launch(void* const* d_in, const int* in_sizes, int n_in,
                              void* d_out, int out_size, void* d_ws, size_t ws_size,
                              hipStream_t stream) {
  // setup_inputs dict order: cls0, reg0, cls1, reg1, cls2, reg2, cls3, reg3, anchors
  const float* cls0 = (const float*)d_in[0];
  const float* reg0 = (const float*)d_in[1];
  const float* cls1 = (const float*)d_in[2];
  const float* reg1 = (const float*)d_in[3];
  const float* cls2 = (const float*)d_in[4];
  const float* reg2 = (const float*)d_in[5];
  const float* cls3 = (const float*)d_in[6];
  const float* reg3 = (const float*)d_in[7];
  const float* anchors = (const float*)d_in[8];
  float* out = (float*)d_out;

  char* ws = (char*)d_ws;
  size_t off = 0;
  auto take = [&](size_t bytes) -> void* {
    off = (off + 255) & ~(size_t)255;
    void* p = ws + off;
    off += bytes;
    return p;
  };
  ulonglong2* trip = (ulonglong2*)take((size_t)64 * TRIPCAP * 16); // 16.8 MB
  u64* sidebuf   = (u64*)take((size_t)64 * SIDECAP * 8);     // 2 MB
  u32* rnzl      = (u32*)take((size_t)64 * LSEG * 4);        // 256 KB
  u64* cand_key  = (u64*)take((size_t)NB * 4096 * 8);        // 512 KB
  float4* sbox   = (float4*)take((size_t)64 * LSEG * 16);    // 1 MB
  float4* boffA  = (float4*)take((size_t)64 * LSEG * 16);    // 1 MB
  float* area    = (float*)take((size_t)64 * LSEG * 4);
  float* score   = (float*)take((size_t)64 * LSEG * 4);
  u64* vmaskl    = (u64*)take((size_t)64 * LCH * 8);
  u64* keptkeys  = (u64*)take((size_t)64 * LSEG * 8);        // 512 KB
  u32* keptpos   = (u32*)take((size_t)64 * LSEG * 4);        // 256 KB
  u32* keptcnt   = (u32*)take((size_t)64 * 4);
  u32* histb     = (u32*)take((size_t)192 * NBUCK * 4);      // 6.3 MB
  u32* counters  = (u32*)take((size_t)64 * 16 * 4);          // 64B-padded
  u32* sidecnt   = (u32*)take((size_t)64 * 16 * 4);          // 64B-padded
  u32* tripcnt   = (u32*)take((size_t)64 * 16 * 4);          // 64B-padded
  u32* state_known = (u32*)take((size_t)64 * 4);
  u32* state_kneed = (u32*)take((size_t)64 * 4);
  (void)ws_size; (void)in_sizes; (void)n_in; (void)out_size;

  k_hist1<<<192, 1024, 0, stream>>>(cls0, cls1, cls2, cls3, histb, out,
                                    cand_key, counters, sidecnt, tripcnt);
  k_pick1<<<64, 1024, 0, stream>>>(histb, state_known, state_kneed);
  k_collect<<<192, 1024, 0, stream>>>(cls0, cls1, cls2, cls3, state_known,
                                      reg0, reg1, reg2, reg3, anchors,
                                      counters, sidecnt, sidebuf, cand_key);
  k_sortdec<<<64, 1024, 0, stream>>>(cand_key, sidebuf, sidecnt, counters,
                                     state_kneed, reg0, reg1, reg2, reg3,
                                     anchors, sbox, boffA, area, score,
                                     vmaskl, rnzl);
  k_maskl<<<64 * NPAIR, 256, 0, stream>>>(boffA, area, trip, tripcnt, rnzl);
  // dynamic LDS: 128 KB mask matrix + 4 KB rnz copy = 135168 B (<= 160 KB/CU)
  k_nmsl<<<64, 64, 135168, stream>>>(trip, tripcnt, rnzl, vmaskl, cand_key,
                                     keptkeys, keptpos, keptcnt);
  k_out<<<64, 1024, 0, stream>>>(keptkeys, keptpos, keptcnt, sbox, score, out);
}

// Round 17
// 125.889 us; speedup vs baseline: 1.1042x; 1.1042x over previous
//
#include <hip/hip_runtime.h>
#include <cstdint>
#include <cstddef>

typedef uint32_t u32;
typedef uint64_t u64;

#define NB 16
#define POSTN 1000
#define PREN 1000
#define LSEG 1024     // per-level segment (1000 candidates + 24 pad)
#define LCH 16        // chunks of 64 per level
#define SIDECAP 4096  // per-task boundary-bucket buffer
#define BSIDE 2048    // per-block LDS side list
#define TRIPCAP (LSEG * LCH)  // per-task triplet capacity = full matrix
#define NPAIR 160     // triangular (chunk,g) pairs: 16+32+48+64
#define NBUCK 8192    // 13-bit histogram buckets
#define BSHIFT 19     // ord >> BSHIFT = bucket

__constant__ int c_N[4]    = {120000, 30000, 7500, 1875};
__constant__ int c_OFF[4]  = {0, 120000, 150000, 157500};
__constant__ int c_HW[4]   = {40000, 10000, 2500, 625};
__constant__ int c_W[4]    = {200, 100, 50, 25};
__constant__ int c_BASE[4] = {0, 1024, 2048, 3072};

__device__ __forceinline__ u32 ord_bits(float f) {
  u32 u = __float_as_uint(f);
  return (u & 0x80000000u) ? ~u : (u | 0x80000000u);
}
__device__ __forceinline__ float inv_ord(u32 o) {
  u32 bits = (o & 0x80000000u) ? (o ^ 0x80000000u) : ~o;
  return __uint_as_float(bits);
}
__device__ __forceinline__ u64 readlane_u64(u64 v, int l) {
  u32 lo = (u32)__builtin_amdgcn_readlane((int)(u32)v, l);
  u32 hi = (u32)__builtin_amdgcn_readlane((int)(u32)(v >> 32), l);
  return (((u64)hi) << 32) | (u64)lo;
}

// 192-block slice map: 8 blocks/task lvl0, 2/task lvl1, 1/task lvl2+3
__device__ __forceinline__ void slice_map(int bid, int& lvl, int& b, int& e0,
                                          int& nsl) {
  if (bid < 128)      { lvl = 0; b = bid >> 3; e0 = (bid & 7) * 15000; nsl = 15000; }
  else if (bid < 160) { lvl = 1; int t = bid - 128; b = t >> 1; e0 = (t & 1) * 15000; nsl = 15000; }
  else if (bid < 176) { lvl = 2; b = bid - 160; e0 = 0; nsl = 7500; }
  else                { lvl = 3; b = bid - 176; e0 = 0; nsl = 1875; }
}

struct DecBox { float x1, y1, x2, y2; int lvl; bool valid; };

__device__ DecBox decode_box(u32 gid, int b,
    const float* __restrict__ reg0, const float* __restrict__ reg1,
    const float* __restrict__ reg2, const float* __restrict__ reg3,
    const float* __restrict__ anchors) {
  int lvl = (gid < 120000u) ? 0 : (gid < 150000u) ? 1 : (gid < 157500u) ? 2 : 3;
  int local = (int)gid - c_OFF[lvl];
  int a = local % 3;
  int cell = local / 3;
  int w = c_W[lvl];
  int hw = c_HW[lvl];
  int y = cell / w;
  int x = cell - y * w;
  const float* reg = (lvl == 0) ? reg0 : (lvl == 1) ? reg1 : (lvl == 2) ? reg2 : reg3;
  size_t base = ((size_t)(b * 12 + a * 4) * (size_t)w + (size_t)y) * (size_t)w + (size_t)x;
  const float CLIPV = 4.135166556742356f; // log(1000/16) as f32
  float dx = reg[base];
  float dy = reg[base + (size_t)hw];
  float dwv = fminf(reg[base + 2 * (size_t)hw], CLIPV);
  float dhv = fminf(reg[base + 3 * (size_t)hw], CLIPV);
  float a0 = anchors[(size_t)gid * 4 + 0];
  float a1 = anchors[(size_t)gid * 4 + 1];
  float a2 = anchors[(size_t)gid * 4 + 2];
  float a3 = anchors[(size_t)gid * 4 + 3];
  float wa = __fsub_rn(a2, a0);
  float ha = __fsub_rn(a3, a1);
  float cxa = __fadd_rn(a0, __fmul_rn(0.5f, wa));
  float cya = __fadd_rn(a1, __fmul_rn(0.5f, ha));
  float pcx = __fadd_rn(__fmul_rn(dx, wa), cxa);
  float pcy = __fadd_rn(__fmul_rn(dy, ha), cya);
  float pw = __fmul_rn(expf(dwv), wa);
  float ph = __fmul_rn(expf(dhv), ha);
  float x1 = __fsub_rn(pcx, __fmul_rn(0.5f, pw));
  float y1 = __fsub_rn(pcy, __fmul_rn(0.5f, ph));
  float x2 = __fadd_rn(pcx, __fmul_rn(0.5f, pw));
  float y2 = __fadd_rn(pcy, __fmul_rn(0.5f, ph));
  x1 = fminf(fmaxf(x1, 0.0f), 800.0f);
  y1 = fminf(fmaxf(y1, 0.0f), 800.0f);
  x2 = fminf(fmaxf(x2, 0.0f), 800.0f);
  y2 = fminf(fmaxf(y2, 0.0f), 800.0f);
  DecBox r;
  r.x1 = x1; r.y1 = y1; r.x2 = x2; r.y2 = y2; r.lvl = lvl;
  r.valid = (__fsub_rn(x2, x1) >= 1.0f) && (__fsub_rn(y2, y1) >= 1.0f);
  return r;
}

// ---------------- K0: zero state ----------------------------------------------
__global__ void k_zero(float* __restrict__ out, u32* __restrict__ counters,
                       u32* __restrict__ sidecnt, u32* __restrict__ tripcnt,
                       u64* __restrict__ cand_key,
                       u32* __restrict__ hist1, u32* __restrict__ state_known,
                       u32* __restrict__ state_kneed) {
  int i = blockIdx.x * blockDim.x + threadIdx.x;
  if (i < NB * POSTN * 5) out[i] = 0.0f;
  if (i < NB * 4096) cand_key[i] = 0ull;
  if (i < 64 * NBUCK) hist1[i] = 0u;
  if (i < 64 * 16) { counters[i] = 0u; sidecnt[i] = 0u; tripcnt[i] = 0u; }
  if (i < 64) { state_known[i] = 0u; state_kneed[i] = (u32)PREN; }
}

// ---------------- K1: top-13-bit histogram straight from cls (float4) ----------
__global__ __launch_bounds__(1024) void k_hist1(
    const float* __restrict__ cls0, const float* __restrict__ cls1,
    const float* __restrict__ cls2, const float* __restrict__ cls3,
    u32* __restrict__ hist1) {
  int lvl, b, e0, nsl;
  slice_map(blockIdx.x, lvl, b, e0, nsl);
  const float* cls = (lvl == 0) ? cls0 : (lvl == 1) ? cls1 : (lvl == 2) ? cls2 : cls3;
  const float* cp = cls + (size_t)b * c_N[lvl];
  int tid = threadIdx.x;
  __shared__ u32 h[NBUCK];
  for (int t = tid; t < NBUCK; t += 1024) h[t] = 0u;
  __syncthreads();
  if (lvl != 3) {
    // base offsets are 16B-aligned for lvl 0..2 (all multiples of 4 elems)
    const float4* cp4 = (const float4*)(cp + e0);
    int n4 = nsl >> 2;
    for (int t = tid; t < n4; t += 1024) {
      float4 v = cp4[t];
      atomicAdd(&h[ord_bits(v.x) >> BSHIFT], 1u);
      atomicAdd(&h[ord_bits(v.y) >> BSHIFT], 1u);
      atomicAdd(&h[ord_bits(v.z) >> BSHIFT], 1u);
      atomicAdd(&h[ord_bits(v.w) >> BSHIFT], 1u);
    }
  } else {
    for (int e = e0 + tid; e < e0 + nsl; e += 1024)
      atomicAdd(&h[ord_bits(cp[e]) >> BSHIFT], 1u);
  }
  __syncthreads();
  int task = lvl * 16 + b;
  for (int t = tid; t < NBUCK; t += 1024) {
    u32 v = h[t];
    if (v) atomicAdd(&hist1[task * NBUCK + t], v);
  }
}

// ---------------- K2: pick boundary bucket — hierarchical O(N) suffix scan -----
__global__ __launch_bounds__(1024) void k_pick1(
    const u32* __restrict__ hist1, u32* __restrict__ state_known,
    u32* __restrict__ state_kneed) {
  int task = blockIdx.x;
  int tid = threadIdx.x;
  __shared__ u32 h[NBUCK];      // 32 KB
  __shared__ u32 spA[1024];
  __shared__ u32 spB[1024];
  __shared__ int sh_t;
  __shared__ u32 sh_above;
  u32 kneed = (u32)PREN;
  for (int t = tid; t < NBUCK; t += 1024) h[t] = hist1[task * NBUCK + t];
  __syncthreads();
  int base = tid << 3;          // 8 buckets per thread
  u32 part = 0;
#pragma unroll
  for (int j = 0; j < 8; ++j) part += h[base + j];
  spA[tid] = part;
  __syncthreads();
  // suffix scan over 1024 partials (ping-pong, 10 rounds)
  u32* cur = spA;
  u32* nxt = spB;
  for (int off = 1; off < 1024; off <<= 1) {
    u32 v = cur[tid] + ((tid + off < 1024) ? cur[tid + off] : 0u);
    nxt[tid] = v;
    __syncthreads();
    u32* tmp = cur; cur = nxt; nxt = tmp;
  }
  // cur[t] = count of elements with bucket >= 8t
  u32 suf = (tid + 1 < 1024) ? cur[tid + 1] : 0u;   // suffix at bucket 8(t+1)
#pragma unroll
  for (int j = 7; j >= 0; --j) {
    u32 s = suf + h[base + j];
    if (s >= kneed && suf < kneed) { sh_t = base + j; sh_above = suf; }
    suf = s;
  }
  __syncthreads();
  if (tid == 0) {
    state_known[task] = (u32)sh_t << BSHIFT;
    state_kneed[task] = kneed - sh_above;   // how many to take from boundary
  }
}

// ---------------- K3: collect — block-local staging, 1 atomic per block --------
__global__ __launch_bounds__(1024) void k_collect(
    const float* __restrict__ cls0, const float* __restrict__ cls1,
    const float* __restrict__ cls2, const float* __restrict__ cls3,
    const u32* __restrict__ state_known,
    const float* __restrict__ reg0, const float* __restrict__ reg1,
    const float* __restrict__ reg2, const float* __restrict__ reg3,
    const float* __restrict__ anchors, u32* __restrict__ counters,
    u32* __restrict__ sidecnt, u64* __restrict__ sidebuf,
    u64* __restrict__ cand_key) {
  int lvl, b, e0, nsl;
  slice_map(blockIdx.x, lvl, b, e0, nsl);
  int task = lvl * 16 + b;
  u32 tb = state_known[task] >> BSHIFT;
  const float* cls = (lvl == 0) ? cls0 : (lvl == 1) ? cls1 : (lvl == 2) ? cls2 : cls3;
  const float* cp = cls + (size_t)b * c_N[lvl];
  int tid = threadIdx.x;
  __shared__ u32 ldef[1024];
  __shared__ u32 lside[BSIDE];
  __shared__ u32 cdef, cside, bdef, bside;
  if (tid == 0) { cdef = 0u; cside = 0u; }
  __syncthreads();
  if (lvl != 3) {
    const float4* cp4 = (const float4*)(cp + e0);
    int n4 = nsl >> 2;
    for (int t = tid; t < n4; t += 1024) {
      float4 v4 = cp4[t];
      int ebase = e0 + (t << 2);
#pragma unroll
      for (int c = 0; c < 4; ++c) {
        float f = (c == 0) ? v4.x : (c == 1) ? v4.y : (c == 2) ? v4.z : v4.w;
        u32 bk = ord_bits(f) >> BSHIFT;
        if (bk < tb) continue;
        if (bk > tb) {
          u32 i = atomicAdd(&cdef, 1u);
          if (i < 1024u) ldef[i] = (u32)(ebase + c);
        } else {
          u32 i = atomicAdd(&cside, 1u);
          if (i < (u32)BSIDE) lside[i] = (u32)(ebase + c);
        }
      }
    }
  } else {
    for (int e = e0 + tid; e < e0 + nsl; e += 1024) {
      u32 bk = ord_bits(cp[e]) >> BSHIFT;
      if (bk < tb) continue;
      if (bk > tb) {
        u32 i = atomicAdd(&cdef, 1u);
        if (i < 1024u) ldef[i] = (u32)e;
      } else {
        u32 i = atomicAdd(&cside, 1u);
        if (i < (u32)BSIDE) lside[i] = (u32)e;
      }
    }
  }
  __syncthreads();
  if (tid == 0) bdef = atomicAdd(&counters[task * 16], min(cdef, 1024u));
  if (tid == 1) bside = atomicAdd(&sidecnt[task * 16], min(cside, (u32)BSIDE));
  __syncthreads();
  int hw = c_HW[lvl], off = c_OFF[lvl];
  u32 nd = min(cdef, 1024u);
  for (u32 i = tid; i < nd; i += 1024) {
    int e = (int)ldef[i];
    int a = e / hw;
    int cell = e - a * hw;
    u32 gid = (u32)(off + cell * 3 + a);
    u64 key = ((u64)ord_bits(cp[e]) << 32) | (u32)(~gid);
    DecBox bx = decode_box(gid, b, reg0, reg1, reg2, reg3, anchors);
    u64 skey = bx.valid ? key : (key & 0xFFFFFFFFull);
    u32 slot = bdef + i;
    if (slot < (u32)PREN)
      cand_key[(size_t)b * 4096 + c_BASE[lvl] + slot] = skey;
  }
  u32 ns = min(cside, (u32)BSIDE);
  for (u32 i = tid; i < ns; i += 1024) {
    int e = (int)lside[i];
    int a = e / hw;
    int cell = e - a * hw;
    u32 gid = (u32)(off + cell * 3 + a);
    u64 key = ((u64)ord_bits(cp[e]) << 32) | (u32)(~gid);
    u32 slot = bside + i;
    if (slot < (u32)SIDECAP) sidebuf[(size_t)task * SIDECAP + slot] = key;
  }
}

// ---------------- K sortdec: fused side-finalize + sort + decode ---------------
__global__ __launch_bounds__(1024) void k_sortdec(
    u64* __restrict__ cand_key, const u64* __restrict__ sidebuf,
    const u32* __restrict__ sidecnt, const u32* __restrict__ counters,
    const u32* __restrict__ state_kneed,
    const float* __restrict__ reg0, const float* __restrict__ reg1,
    const float* __restrict__ reg2, const float* __restrict__ reg3,
    const float* __restrict__ anchors,
    float4* __restrict__ sbox, float4* __restrict__ boffA,
    float* __restrict__ area, float* __restrict__ score,
    u64* __restrict__ vmaskl, u32* __restrict__ rnzl) {
  int bl = blockIdx.x;                 // b*4 + lvl
  int b = bl >> 2;
  int lvl = bl & 3;
  int task = lvl * 16 + b;
  int tid = threadIdx.x;
  // zero rnzl for this (b,lvl) — consumed (atomicOr) by k_maskl after us
  rnzl[(size_t)bl * LSEG + tid] = 0u;
  __shared__ u64 sside[SIDECAP];       // 32 KB
  __shared__ u64 sk[LSEG];             // 8 KB
  u32 nside = min(sidecnt[task * 16], (u32)SIDECAP);
  u32 kneed = state_kneed[task];
  u32 nab = counters[task * 16];       // nab + kneed == 1000 by construction
  u32 np2 = 64;
  while (np2 < nside) np2 <<= 1;
  for (u32 i = tid; i < np2; i += 1024)
    sside[i] = (i < nside) ? sidebuf[(size_t)task * SIDECAP + i] : 0ull;
  __syncthreads();
  // sort side keys desc (raw keys — top-k selection is pre-validity)
  for (u32 k = 2; k <= np2; k <<= 1) {
    for (u32 j = k >> 1; j > 0; j >>= 1) {
      for (u32 t = tid; t < np2 / 2; t += 1024) {
        u32 i = 2u * t - (t & (j - 1u));
        u32 l2 = i | j;
        u64 av = sside[i], bv = sside[l2];
        bool up = ((i & k) == 0u);
        if (up ? (av < bv) : (av > bv)) { sside[i] = bv; sside[l2] = av; }
      }
      __syncthreads();
    }
  }
  // validity-adjust the selected top-kneed side keys (in place, own slot only)
  if (tid < (int)kneed) {
    u64 key = sside[tid];
    u32 gid = ~((u32)key);
    DecBox bx = decode_box(gid, b, reg0, reg1, reg2, reg3, anchors);
    sside[tid] = bx.valid ? key : (key & 0xFFFFFFFFull);
  }
  u64 defk = (tid < (int)nab)
                 ? cand_key[(size_t)b * 4096 + c_BASE[lvl] + tid] : 0ull;
  __syncthreads();
  u64 kv = defk;
  if (tid >= (int)nab && tid < (int)(nab + kneed)) kv = sside[tid - nab];
  sk[tid] = kv;
  __syncthreads();
  // main 1024 bitonic sort desc
  for (u32 k = 2; k <= LSEG; k <<= 1) {
    for (u32 j = k >> 1; j > 0; j >>= 1) {
      if (tid < LSEG / 2) {
        u32 t = (u32)tid;
        u32 i = 2u * t - (t & (j - 1u));
        u32 l2 = i | j;
        u64 av = sk[i], bv = sk[l2];
        bool up = ((i & k) == 0u);
        if (up ? (av < bv) : (av > bv)) { sk[i] = bv; sk[l2] = av; }
      }
      __syncthreads();
    }
  }
  // write back sorted keys (k_nmsl reads them for kept compaction)
  u64 key = sk[tid];
  cand_key[(size_t)bl * LSEG + tid] = key;
  // decode payloads
  float4 bx4 = make_float4(0.f, 0.f, 0.f, 0.f);
  float4 bo4 = make_float4(0.f, 0.f, 0.f, 0.f);
  float ar = 0.f, sc = 0.f;
  bool vflag = false;
  if (key != 0ull) {
    u32 gid = ~((u32)key);
    vflag = (key >> 32) != 0ull;
    DecBox bx = decode_box(gid, b, reg0, reg1, reg2, reg3, anchors);
    bx4 = make_float4(bx.x1, bx.y1, bx.x2, bx.y2);
    float offv = __fmul_rn((float)bx.lvl, 801.0f);
    bo4 = make_float4(__fadd_rn(bx.x1, offv), __fadd_rn(bx.y1, offv),
                      __fadd_rn(bx.x2, offv), __fadd_rn(bx.y2, offv));
    ar = __fmul_rn(__fsub_rn(bo4.z, bo4.x), __fsub_rn(bo4.w, bo4.y));
    if (vflag) {
      float logit = inv_ord((u32)(key >> 32));
      sc = 1.0f / (1.0f + expf(-logit));
    }
  }
  size_t gi = (size_t)bl * LSEG + tid;
  sbox[gi] = bx4;
  boffA[gi] = bo4;
  area[gi] = ar;
  score[gi] = sc;
  u64 bal = __ballot(vflag ? 1 : 0);
  if ((tid & 63) == 0) vmaskl[bl * LCH + (tid >> 6)] = bal;
}

// ---------------- K maskl: triangular-mapped IoU → compact triplet list --------
// RN(inter/uni) > 0.7f  <=>  inter/uni >= B, B = 0.7f + 2^-25 (tie rounds up).
// B*(double)uni is exact (25x24 bits <= 53); comparison is bit-equivalent.
#define RPB 16
__global__ __launch_bounds__(256) void k_maskl(
    const float4* __restrict__ boffA, const float* __restrict__ area,
    ulonglong2* __restrict__ trip, u32* __restrict__ tripcnt,
    u32* __restrict__ rnzl) {
  const double Bd = 0x1.6666661p-1;   // 0.7000000178813934326171875
  int bg = blockIdx.x;
  int bl = bg / NPAIR;
  int p = bg - bl * NPAIR;
  // triangular (chunk,g) pairs: chunk c covers row-groups g < (c+1)*16
  int chunk, g;
  if (p < 16)      { chunk = 0; g = p; }
  else if (p < 48) { chunk = 1; g = p - 16; }
  else if (p < 96) { chunk = 2; g = p - 48; }
  else             { chunk = 3; g = p - 96; }
  int row0 = g * RPB;
  int tid = threadIdx.x;
  int wave = tid >> 6;
  int lane = tid & 63;
  __shared__ float4 rb[RPB];
  __shared__ float ra[RPB];
  __shared__ ulonglong2 stage[RPB * 4];   // max 64 nonzero words per block
  __shared__ u32 scount, sbase;
  if (tid == 0) scount = 0u;
  if (tid < RPB) {
    rb[tid] = boffA[(size_t)bl * LSEG + row0 + tid];
    ra[tid] = area[(size_t)bl * LSEG + row0 + tid];
  }
  __syncthreads();
  int wword = chunk * 4 + wave;
  int wmaxj = chunk * 256 + wave * 64 + 63;   // this wave's max column
  int j = chunk * 256 + tid;
  float4 cb = boffA[(size_t)bl * LSEG + j];
  float ca = area[(size_t)bl * LSEG + j];
  if (wmaxj > row0) {
#pragma unroll
    for (int rr = 0; rr < RPB; ++rr) {
      int i = row0 + rr;
      if (wmaxj <= i) continue;
      float4 rbb = rb[rr];
      float ria = ra[rr];
      float ix1 = fmaxf(cb.x, rbb.x);
      float iy1 = fmaxf(cb.y, rbb.y);
      float ix2 = fminf(cb.z, rbb.z);
      float iy2 = fminf(cb.w, rbb.w);
      float inter = __fmul_rn(fmaxf(__fsub_rn(ix2, ix1), 0.0f),
                              fmaxf(__fsub_rn(iy2, iy1), 0.0f));
      float uni = __fsub_rn(__fadd_rn(ca, ria), inter);
      bool pred = (j > i) && (inter > 0.0f) &&
                  ((double)inter >= Bd * (double)uni);
      u64 bal = __ballot(pred ? 1 : 0);
      if (lane == 0 && bal) {
        u32 sidx = atomicAdd(&scount, 1u);
        ulonglong2 e;
        e.x = bal;
        e.y = (u64)(u32)(i * LCH + wword);
        stage[sidx] = e;
        atomicOr(&rnzl[(size_t)bl * LSEG + i], 1u << wword);
      }
    }
  }
  __syncthreads();
  if (tid == 0 && scount) sbase = atomicAdd(&tripcnt[bl * 16], scount);
  __syncthreads();
  for (u32 t = tid; t < scount; t += 256)
    trip[(size_t)bl * TRIPCAP + sbase + t] = stage[t];
}

// ---------------- K nmsl: greedy NMS — full mask matrix in LDS -----------------
__global__ __launch_bounds__(64) void k_nmsl(
    const ulonglong2* __restrict__ trip, const u32* __restrict__ tripcnt,
    const u32* __restrict__ rnzl, const u64* __restrict__ vmaskl,
    const u64* __restrict__ cand_key,
    u64* __restrict__ keptkeys, u32* __restrict__ keptpos,
    u32* __restrict__ keptcnt) {
  int bl = blockIdx.x;
  int lane = threadIdx.x;
  extern __shared__ char smem[];
  u64* lmask = (u64*)smem;                       // [LSEG*LCH] = 128 KB
  u32* rnzL  = (u32*)(smem + (size_t)LSEG * LCH * 8);  // [LSEG] = 4 KB
  // zero the matrix (16B LDS writes), copy rnzl (coalesced global)
  ulonglong2 z2; z2.x = 0ull; z2.y = 0ull;
  ulonglong2* lm2 = (ulonglong2*)lmask;
  for (int t = lane; t < LSEG * LCH / 2; t += 64) lm2[t] = z2;
  for (int t = lane; t < LSEG; t += 64) rnzL[t] = rnzl[(size_t)bl * LSEG + t];
  u64 vword = (lane < LCH) ? vmaskl[bl * LCH + lane] : 0ull;
  __syncthreads();
  // scatter triplets (unique (row,word) targets — order-independent)
  u32 tc = tripcnt[bl * 16];
  for (u32 t = lane; t < tc; t += 64) {
    ulonglong2 e = trip[(size_t)bl * TRIPCAP + t];
    lmask[(u32)e.y] = e.x;
  }
  __syncthreads();
  u64 supp = 0ull;   // lane w<16 holds suppression word w
  u64 keep = 0ull;   // lane w<16 holds keep word w
  for (int W = 0; W < LCH; ++W) {
    int c0 = W << 6;
    // independent LDS reads issue early; latency hides under the shfl chain
    u32 rzW = rnzL[c0 + lane];                      // rnz of row c0+lane
    u64 dchW = lmask[(size_t)(c0 + lane) * LCH + W];  // diagonal word
    u64 s = __shfl(supp, W);
    u64 v = __shfl(vword, W);
    // greedy resolve: scalar readlane over suppressor rows only
    u64 pending = v & ~s;
    u64 kw = 0ull;
    u64 suppressors = __ballot((dchW & pending) != 0ull) & pending;
    while (pending) {
      u64 sp = pending & suppressors;
      if (!sp) { kw |= pending; break; }
      int q = __builtin_ctzll(sp);
      u64 below = pending & ((1ull << q) - 1ull);
      kw |= below | (1ull << q);
      u64 supq = readlane_u64(dchW, q);
      pending &= ~supq & ~below & ~(1ull << q);
    }
    // sparse apply: kept rows with words beyond W; 4-deep batched LDS reads
    u64 kk = __ballot(((rzW >> W) >> 1) != 0u) & kw;
    bool ld = (lane < LCH);
    u64 acc = 0ull;
    while (kk) {
      int q0 = __builtin_ctzll(kk); kk &= kk - 1ull;
      u64 m0 = ld ? lmask[(size_t)(c0 + q0) * LCH + lane] : 0ull;
      u64 m1 = 0ull, m2 = 0ull, m3 = 0ull;
      if (kk) {
        int q1 = __builtin_ctzll(kk); kk &= kk - 1ull;
        m1 = ld ? lmask[(size_t)(c0 + q1) * LCH + lane] : 0ull;
      }
      if (kk) {
        int q2 = __builtin_ctzll(kk); kk &= kk - 1ull;
        m2 = ld ? lmask[(size_t)(c0 + q2) * LCH + lane] : 0ull;
      }
      if (kk) {
        int q3 = __builtin_ctzll(kk); kk &= kk - 1ull;
        m3 = ld ? lmask[(size_t)(c0 + q3) * LCH + lane] : 0ull;
      }
      acc |= (m0 | m1) | (m2 | m3);
    }
    supp |= acc;
    if (lane == W) keep = kw;
  }
  // compact kept: prefix popcount across lanes
  int pc = __popcll(keep);
  int incl = pc;
  for (int d = 1; d < 64; d <<= 1) {
    int t = __shfl_up(incl, d);
    if (lane >= d) incl += t;
  }
  int r = incl - pc;
  u64 kk = keep;
  while (kk) {
    int bit = __builtin_ctzll(kk);
    kk &= kk - 1ull;
    int p = lane * 64 + bit;
    keptkeys[(size_t)bl * LSEG + r] = cand_key[(size_t)bl * LSEG + p];
    keptpos[(size_t)bl * LSEG + r] = (u32)p;
    ++r;
  }
  if (lane == 63) keptcnt[bl] = (u32)incl;
}

// ---------------- K out: global rank via cross-level binary search -------------
__global__ __launch_bounds__(1024) void k_out(
    const u64* __restrict__ keptkeys, const u32* __restrict__ keptpos,
    const u32* __restrict__ keptcnt, const float4* __restrict__ sbox,
    const float* __restrict__ score, float* __restrict__ out) {
  int bl = blockIdx.x;
  int b = bl >> 2;
  int l = bl & 3;
  int r = threadIdx.x;
  u32 cnt = keptcnt[bl];
  if (r >= (int)cnt) return;
  u64 K = keptkeys[(size_t)bl * LSEG + r];
  int rank = r;
#pragma unroll
  for (int dl = 0; dl < 4; ++dl) {
    if (dl == l) continue;
    int obl = (b << 2) | dl;
    const u64* arr = keptkeys + (size_t)obl * LSEG;
    int lo = 0, hi = (int)keptcnt[obl];
    while (lo < hi) {
      int mid = (lo + hi) >> 1;
      if (arr[mid] > K) lo = mid + 1; else hi = mid;
    }
    rank += lo;
  }
  if (rank < POSTN) {
    u32 p = keptpos[(size_t)bl * LSEG + r];
    float4 bx = sbox[(size_t)bl * LSEG + p];
    size_t ob = ((size_t)b * POSTN + (size_t)rank) * 4;
    out[ob + 0] = bx.x;
    out[ob + 1] = bx.y;
    out[ob + 2] = bx.z;
    out[ob + 3] = bx.w;
    out[(size_t)NB * POSTN * 4 + (size_t)b * POSTN + (size_t)rank] =
        score[(size_t)bl * LSEG + p];
  }
}

extern "C" void kernel_launch(void* const* d_in, const int* in_sizes, int n_in,
                              void* d_out, int out_size, void* d_ws, size_t ws_size,
                              hipStream_t stream) {
  // setup_inputs dict order: cls0, reg0, cls1, reg1, cls2, reg2, cls3, reg3, anchors
  const float* cls0 = (const float*)d_in[0];
  const float* reg0 = (const float*)d_in[1];
  const float* cls1 = (const float*)d_in[2];
  const float* reg1 = (const float*)d_in[3];
  const float* cls2 = (const float*)d_in[4];
  const float* reg2 = (const float*)d_in[5];
  const float* cls3 = (const float*)d_in[6];
  const float* reg3 = (const float*)d_in[7];
  const float* anchors = (const float*)d_in[8];
  float* out = (float*)d_out;

  char* ws = (char*)d_ws;
  size_t off = 0;
  auto take = [&](size_t bytes) -> void* {
    off = (off + 255) & ~(size_t)255;
    void* p = ws + off;
    off += bytes;
    return p;
  };
  ulonglong2* trip = (ulonglong2*)take((size_t)64 * TRIPCAP * 16); // 16.8 MB
  u64* sidebuf   = (u64*)take((size_t)64 * SIDECAP * 8);     // 2 MB
  u32* rnzl      = (u32*)take((size_t)64 * LSEG * 4);        // 256 KB
  u64* cand_key  = (u64*)take((size_t)NB * 4096 * 8);        // 512 KB
  float4* sbox   = (float4*)take((size_t)64 * LSEG * 16);    // 1 MB
  float4* boffA  = (float4*)take((size_t)64 * LSEG * 16);    // 1 MB
  float* area    = (float*)take((size_t)64 * LSEG * 4);
  float* score   = (float*)take((size_t)64 * LSEG * 4);
  u64* vmaskl    = (u64*)take((size_t)64 * LCH * 8);
  u64* keptkeys  = (u64*)take((size_t)64 * LSEG * 8);        // 512 KB
  u32* keptpos   = (u32*)take((size_t)64 * LSEG * 4);        // 256 KB
  u32* keptcnt   = (u32*)take((size_t)64 * 4);
  u32* hist1     = (u32*)take((size_t)64 * NBUCK * 4);       // 2 MB
  u32* counters  = (u32*)take((size_t)64 * 16 * 4);          // 64B-padded
  u32* sidecnt   = (u32*)take((size_t)64 * 16 * 4);          // 64B-padded
  u32* tripcnt   = (u32*)take((size_t)64 * 16 * 4);          // 64B-padded
  u32* state_known = (u32*)take((size_t)64 * 4);
  u32* state_kneed = (u32*)take((size_t)64 * 4);
  (void)ws_size; (void)in_sizes; (void)n_in; (void)out_size;

  k_zero<<<2048, 256, 0, stream>>>(out, counters, sidecnt, tripcnt, cand_key,
                                   hist1, state_known, state_kneed);
  k_hist1<<<192, 1024, 0, stream>>>(cls0, cls1, cls2, cls3, hist1);
  k_pick1<<<64, 1024, 0, stream>>>(hist1, state_known, state_kneed);
  k_collect<<<192, 1024, 0, stream>>>(cls0, cls1, cls2, cls3, state_known,
                                      reg0, reg1, reg2, reg3, anchors,
                                      counters, sidecnt, sidebuf, cand_key);
  k_sortdec<<<64, 1024, 0, stream>>>(cand_key, sidebuf, sidecnt, counters,
                                     state_kneed, reg0, reg1, reg2, reg3,
                                     anchors, sbox, boffA, area, score,
                                     vmaskl, rnzl);
  k_maskl<<<64 * NPAIR, 256, 0, stream>>>(boffA, area, trip, tripcnt, rnzl);
  // dynamic LDS: 128 KB mask matrix + 4 KB rnz copy = 135168 B (<= 160 KB/CU)
  k_nmsl<<<64, 64, 135168, stream>>>(trip, tripcnt, rnzl, vmaskl, cand_key,
                                     keptkeys, keptpos, keptcnt);
  k_out<<<64, 1024, 0, stream>>>(keptkeys, keptpos, keptcnt, sbox, score, out);
}